// Round 1
// baseline (534.608 us; speedup 1.0000x reference)
//
#include <hip/hip_runtime.h>
#include <hip/hip_bf16.h>

// Problem constants (reference: IDIM1=IDIM2=512, HDIM=256, B=16, N=32, T=256)
#define BB 16
#define NN 32
#define TT 256
#define HH 256
#define DD 512
#define TILE_T 64
#define EPSF 1e-5f

// ---------------------------------------------------------------------------
// Kernel 1: h = relu(x @ W + b) for both h1 (512 rows) and h2 (4096 rows).
// blocks 0..31   -> h1 rows (16 rows/block)
// blocks 32..287 -> h2 rows (16 rows/block)
// 256 threads, thread j owns output column j; 16 row accumulators.
// ---------------------------------------------------------------------------
__global__ __launch_bounds__(256) void gemm_h12_kernel(
    const float* __restrict__ x1, const float* __restrict__ x2,
    const float* __restrict__ W1, const float* __restrict__ b1,
    const float* __restrict__ W2, const float* __restrict__ b2,
    float* __restrict__ h1, float* __restrict__ h2)
{
    __shared__ float xs[16][DD];   // 32 KB

    const int j = threadIdx.x;
    const float* x; const float* W; const float* bias; float* h; int row0;
    if (blockIdx.x < 32) {
        x = x1; W = W1; bias = b1; h = h1; row0 = blockIdx.x * 16;
    } else {
        x = x2; W = W2; bias = b2; h = h2; row0 = (blockIdx.x - 32) * 16;
    }

    // Stage 16 rows of x (16*512 floats) into LDS with float4 loads.
    {
        const float4* xg = reinterpret_cast<const float4*>(x + (size_t)row0 * DD);
        float4* xl = reinterpret_cast<float4*>(&xs[0][0]);
#pragma unroll
        for (int i = 0; i < 8; ++i) xl[j + 256 * i] = xg[j + 256 * i];
    }
    __syncthreads();

    float acc[16];
#pragma unroll
    for (int r = 0; r < 16; ++r) acc[r] = 0.0f;

    for (int k = 0; k < DD; k += 4) {
        const float w0 = W[(size_t)(k + 0) * HH + j];
        const float w1 = W[(size_t)(k + 1) * HH + j];
        const float w2 = W[(size_t)(k + 2) * HH + j];
        const float w3 = W[(size_t)(k + 3) * HH + j];
#pragma unroll
        for (int r = 0; r < 16; ++r) {
            const float4 xr = *reinterpret_cast<const float4*>(&xs[r][k]);
            float a = acc[r];
            a = fmaf(xr.x, w0, a);
            a = fmaf(xr.y, w1, a);
            a = fmaf(xr.z, w2, a);
            a = fmaf(xr.w, w3, a);
            acc[r] = a;
        }
    }

    const float bb = bias[j];
#pragma unroll
    for (int r = 0; r < 16; ++r) {
        const float v = acc[r] + bb;
        h[(size_t)(row0 + r) * HH + j] = v > 0.0f ? v : 0.0f;
    }
}

// ---------------------------------------------------------------------------
// Kernel 2: fully fused per (b,n):
//   A = LN0(h1[b,n,:] * h2[b,t,:])   (rows t in tile of 64)
//   Y = A @ W3 + b3
//   out = relu(LN1(Y))
// 256 threads = 4 waves. LDS holds one 64x256 f32 tile (A, reused for Y).
// ---------------------------------------------------------------------------
__global__ __launch_bounds__(256) void fused_main_kernel(
    const float* __restrict__ h1, const float* __restrict__ h2,
    const float* __restrict__ W3, const float* __restrict__ b3,
    const float* __restrict__ g0, const float* __restrict__ be0,
    const float* __restrict__ g1, const float* __restrict__ be1,
    float* __restrict__ out)
{
    __shared__ float Asm[TILE_T][HH];   // 64 KB exactly

    const int tid  = threadIdx.x;
    const int wave = tid >> 6;
    const int lane = tid & 63;
    const int b    = blockIdx.x >> 5;   // N = 32
    const int n    = blockIdx.x & 31;

    // Per-lane constants: lane l owns columns 4l..4l+3 in LN phases.
    float4 h1v, g0v, be0v, g1v, be1v;
    {
        const float* h1row = h1 + ((size_t)b * NN + n) * HH;
        h1v  = *reinterpret_cast<const float4*>(h1row + 4 * lane);
        g0v  = *reinterpret_cast<const float4*>(g0  + 4 * lane);
        be0v = *reinterpret_cast<const float4*>(be0 + 4 * lane);
        g1v  = *reinterpret_cast<const float4*>(g1  + 4 * lane);
        be1v = *reinterpret_cast<const float4*>(be1 + 4 * lane);
    }

    // GEMM mapping: thread = (jj in [0,128), rh in {0,1});
    // owns columns {jj, jj+128} for rows rh*32 .. rh*32+31 of the tile.
    const int jj = tid & 127;
    const int rh = tid >> 7;
    const float b3a = b3[jj];
    const float b3b = b3[jj + 128];

    const float* h2b   = h2 + (size_t)b * TT * HH;
    float* outbn = out + (((size_t)b * NN + n) * TT) * HH;

    for (int t0 = 0; t0 < TT; t0 += TILE_T) {
        // ---- Phase A: per-wave LN of Hadamard rows -> Asm -----------------
#pragma unroll 2
        for (int i = 0; i < 16; ++i) {
            const int r = wave * 16 + i;
            const int t = t0 + r;
            float4 v = *reinterpret_cast<const float4*>(h2b + (size_t)t * HH + 4 * lane);
            v.x *= h1v.x; v.y *= h1v.y; v.z *= h1v.z; v.w *= h1v.w;
            float s = v.x + v.y + v.z + v.w;
            float q = v.x * v.x + v.y * v.y + v.z * v.z + v.w * v.w;
#pragma unroll
            for (int off = 32; off >= 1; off >>= 1) {
                s += __shfl_xor(s, off, 64);
                q += __shfl_xor(q, off, 64);
            }
            const float mu  = s * (1.0f / HH);
            const float var = q * (1.0f / HH) - mu * mu;
            const float rs  = rsqrtf(var + EPSF);
            float4 a;
            a.x = (v.x - mu) * rs * g0v.x + be0v.x;
            a.y = (v.y - mu) * rs * g0v.y + be0v.y;
            a.z = (v.z - mu) * rs * g0v.z + be0v.z;
            a.w = (v.w - mu) * rs * g0v.w + be0v.w;
            *reinterpret_cast<float4*>(&Asm[r][4 * lane]) = a;
        }
        __syncthreads();

        // ---- GEMM: Y = A @ W3 + b3 (register accumulators) ----------------
        float acc0[32], acc1[32];
#pragma unroll
        for (int r2 = 0; r2 < 32; ++r2) { acc0[r2] = b3a; acc1[r2] = b3b; }

        const float* Arow = &Asm[rh * 32][0];
        for (int k = 0; k < HH; k += 4) {
            const float w00 = W3[(size_t)(k + 0) * HH + jj];
            const float w01 = W3[(size_t)(k + 1) * HH + jj];
            const float w02 = W3[(size_t)(k + 2) * HH + jj];
            const float w03 = W3[(size_t)(k + 3) * HH + jj];
            const float w10 = W3[(size_t)(k + 0) * HH + jj + 128];
            const float w11 = W3[(size_t)(k + 1) * HH + jj + 128];
            const float w12 = W3[(size_t)(k + 2) * HH + jj + 128];
            const float w13 = W3[(size_t)(k + 3) * HH + jj + 128];
#pragma unroll
            for (int r2 = 0; r2 < 32; ++r2) {
                const float4 a = *reinterpret_cast<const float4*>(Arow + r2 * HH + k);
                float c0 = acc0[r2];
                float c1 = acc1[r2];
                c0 = fmaf(a.x, w00, c0);
                c0 = fmaf(a.y, w01, c0);
                c0 = fmaf(a.z, w02, c0);
                c0 = fmaf(a.w, w03, c0);
                c1 = fmaf(a.x, w10, c1);
                c1 = fmaf(a.y, w11, c1);
                c1 = fmaf(a.z, w12, c1);
                c1 = fmaf(a.w, w13, c1);
                acc0[r2] = c0;
                acc1[r2] = c1;
            }
        }
        __syncthreads();   // everyone done reading A

        // ---- Write Y back into the LDS tile --------------------------------
#pragma unroll
        for (int r2 = 0; r2 < 32; ++r2) {
            Asm[rh * 32 + r2][jj]       = acc0[r2];
            Asm[rh * 32 + r2][jj + 128] = acc1[r2];
        }
        __syncthreads();

        // ---- LN1 + relu + coalesced store ---------------------------------
#pragma unroll 2
        for (int i = 0; i < 16; ++i) {
            const int r = wave * 16 + i;
            const int t = t0 + r;
            const float4 y = *reinterpret_cast<const float4*>(&Asm[r][4 * lane]);
            float s = y.x + y.y + y.z + y.w;
            float q = y.x * y.x + y.y * y.y + y.z * y.z + y.w * y.w;
#pragma unroll
            for (int off = 32; off >= 1; off >>= 1) {
                s += __shfl_xor(s, off, 64);
                q += __shfl_xor(q, off, 64);
            }
            const float mu  = s * (1.0f / HH);
            const float var = q * (1.0f / HH) - mu * mu;
            const float rs  = rsqrtf(var + EPSF);
            float4 o;
            o.x = fmaxf((y.x - mu) * rs * g1v.x + be1v.x, 0.0f);
            o.y = fmaxf((y.y - mu) * rs * g1v.y + be1v.y, 0.0f);
            o.z = fmaxf((y.z - mu) * rs * g1v.z + be1v.z, 0.0f);
            o.w = fmaxf((y.w - mu) * rs * g1v.w + be1v.w, 0.0f);
            *reinterpret_cast<float4*>(outbn + (size_t)t * HH + 4 * lane) = o;
        }
        __syncthreads();   // protect Asm before next tile overwrites it
    }
}

// ---------------------------------------------------------------------------
extern "C" void kernel_launch(void* const* d_in, const int* in_sizes, int n_in,
                              void* d_out, int out_size, void* d_ws, size_t ws_size,
                              hipStream_t stream) {
    const float* x1  = (const float*)d_in[0];
    const float* x2  = (const float*)d_in[1];
    const float* W1  = (const float*)d_in[2];
    const float* b1  = (const float*)d_in[3];
    const float* W2  = (const float*)d_in[4];
    const float* b2  = (const float*)d_in[5];
    const float* W3  = (const float*)d_in[6];
    const float* b3  = (const float*)d_in[7];
    const float* g0  = (const float*)d_in[8];
    const float* be0 = (const float*)d_in[9];
    const float* g1  = (const float*)d_in[10];
    const float* be1 = (const float*)d_in[11];
    float* out = (float*)d_out;

    // Workspace layout: h1 [512*256] then h2 [4096*256] floats (4.5 MB total).
    float* h1 = (float*)d_ws;
    float* h2 = h1 + (size_t)BB * NN * HH;

    // h1: 512 rows -> 32 blocks; h2: 4096 rows -> 256 blocks.
    hipLaunchKernelGGL(gemm_h12_kernel, dim3(288), dim3(256), 0, stream,
                       x1, x2, W1, b1, W2, b2, h1, h2);

    // One block per (b, n): 16*32 = 512 blocks.
    hipLaunchKernelGGL(fused_main_kernel, dim3(512), dim3(256), 0, stream,
                       h1, h2, W3, b3, g0, be0, g1, be1, out);
}

// Round 5
// 426.744 us; speedup vs baseline: 1.2528x; 1.2528x over previous
//
#include <hip/hip_runtime.h>
#include <hip/hip_bf16.h>
#include <stdint.h>

#define BB 16
#define NN 32
#define TT 256
#define HH 256
#define DD 512
#define EPSF 1e-5f

#define TROWS 32   // T-tile rows per block

// ---------------------------------------------------------------------------
// Kernel 1: prep. h = relu(x @ W + b) for h1 (512 rows) and h2 (4096 rows).
//  blocks  0..63  : h1, 8 rows/block
//  blocks 64..575 : h2, 8 rows/block
// thread = (c2 = tid&127 -> cols {2c2,2c2+1}, rg = tid>>7 -> rows rg*4..+3).
// All LDS reads are wave-uniform broadcasts of x rows.
// ---------------------------------------------------------------------------
__global__ __launch_bounds__(256) void prep_kernel(
    const float* __restrict__ x1, const float* __restrict__ x2,
    const float* __restrict__ W1, const float* __restrict__ b1,
    const float* __restrict__ W2, const float* __restrict__ b2,
    float* __restrict__ h1, float* __restrict__ h2)
{
    __shared__ float xs[8][DD];   // 16 KB

    const int blk = blockIdx.x;
    const int tid = threadIdx.x;

    const float* x; const float* W; const float* bias; float* h; int row0;
    if (blk < 64) { x = x1; W = W1; bias = b1; h = h1; row0 = blk * 8; }
    else          { x = x2; W = W2; bias = b2; h = h2; row0 = (blk - 64) * 8; }

    {
        const float4* xg = reinterpret_cast<const float4*>(x + (size_t)row0 * DD);
        float4* xl = reinterpret_cast<float4*>(&xs[0][0]);
#pragma unroll
        for (int i = 0; i < 4; ++i) xl[tid + 256 * i] = xg[tid + 256 * i];
    }
    __syncthreads();

    const int c2 = tid & 127;
    const int rg = tid >> 7;

    float a0[4], a1[4];
#pragma unroll
    for (int r = 0; r < 4; ++r) { a0[r] = 0.0f; a1[r] = 0.0f; }

    for (int k = 0; k < DD; k += 4) {
        float2 w0 = *reinterpret_cast<const float2*>(&W[(size_t)(k + 0) * HH + 2 * c2]);
        float2 w1 = *reinterpret_cast<const float2*>(&W[(size_t)(k + 1) * HH + 2 * c2]);
        float2 w2 = *reinterpret_cast<const float2*>(&W[(size_t)(k + 2) * HH + 2 * c2]);
        float2 w3 = *reinterpret_cast<const float2*>(&W[(size_t)(k + 3) * HH + 2 * c2]);
#pragma unroll
        for (int r = 0; r < 4; ++r) {
            const float4 xv = *reinterpret_cast<const float4*>(&xs[rg * 4 + r][k]);
            float s0 = a0[r], s1 = a1[r];
            s0 = fmaf(xv.x, w0.x, s0); s1 = fmaf(xv.x, w0.y, s1);
            s0 = fmaf(xv.y, w1.x, s0); s1 = fmaf(xv.y, w1.y, s1);
            s0 = fmaf(xv.z, w2.x, s0); s1 = fmaf(xv.z, w2.y, s1);
            s0 = fmaf(xv.w, w3.x, s0); s1 = fmaf(xv.w, w3.y, s1);
            a0[r] = s0; a1[r] = s1;
        }
    }

    const float2 bb = *reinterpret_cast<const float2*>(&bias[2 * c2]);
#pragma unroll
    for (int r = 0; r < 4; ++r) {
        float2 o;
        o.x = fmaxf(a0[r] + bb.x, 0.0f);
        o.y = fmaxf(a1[r] + bb.y, 0.0f);
        *reinterpret_cast<float2*>(&h[(size_t)(row0 + rg * 4 + r) * HH + 2 * c2]) = o;
    }
}

// ---------------------------------------------------------------------------
// Kernel 2: fused main, all-f32 (R1-proven math, restructured for occupancy).
// One block per (b, n, 32-row T-tile) -> grid 4096. 256 threads = 4 waves.
//   Phase A: A = LN0(h1[b,n,:] * h2[b,t,:]) -> f32 LDS tile [32][256]
//   GEMM:    Y = A @ W3 + b3  (VALU; A reads are wave-uniform b128 broadcasts)
//   Phase C: Y -> LDS overlay, LN1 + relu -> out
// LDS = 32 KB static.
// ---------------------------------------------------------------------------
__global__ __launch_bounds__(256) void fused_f32_kernel(
    const float* __restrict__ h1, const float* __restrict__ h2,
    const float* __restrict__ W3, const float* __restrict__ b3,
    const float* __restrict__ g0, const float* __restrict__ be0,
    const float* __restrict__ g1, const float* __restrict__ be1,
    float* __restrict__ out)
{
    __shared__ float Asm[TROWS][HH];          // 32 KB; Ysm overlays same space
    float* Ysm = &Asm[0][0];

    const int tid  = threadIdx.x;
    const int wave = tid >> 6;
    const int lane = tid & 63;
    const int blk  = blockIdx.x;
    const int tile = blk & 7;          // 8 tiles of 32 rows
    const int n    = (blk >> 3) & 31;
    const int b    = blk >> 8;

    // ---- Phase A: Hadamard + LN0 -> f32 A-tile ----------------------------
    {
        const float* h1row = h1 + ((size_t)b * NN + n) * HH;
        const float4 h1v  = *reinterpret_cast<const float4*>(h1row + 4 * lane);
        const float4 g0v  = *reinterpret_cast<const float4*>(g0  + 4 * lane);
        const float4 be0v = *reinterpret_cast<const float4*>(be0 + 4 * lane);
        const float* h2b  = h2 + ((size_t)b * TT + tile * TROWS) * HH;

#pragma unroll 2
        for (int i = 0; i < 8; ++i) {
            const int r = wave * 8 + i;
            float4 v = *reinterpret_cast<const float4*>(h2b + (size_t)r * HH + 4 * lane);
            v.x *= h1v.x; v.y *= h1v.y; v.z *= h1v.z; v.w *= h1v.w;
            float s = v.x + v.y + v.z + v.w;
            float q = v.x * v.x + v.y * v.y + v.z * v.z + v.w * v.w;
#pragma unroll
            for (int off = 32; off >= 1; off >>= 1) {
                s += __shfl_xor(s, off, 64);
                q += __shfl_xor(q, off, 64);
            }
            const float mu  = s * (1.0f / HH);
            const float var = q * (1.0f / HH) - mu * mu;
            const float rs  = rsqrtf(var + EPSF);
            float4 a;
            a.x = (v.x - mu) * rs * g0v.x + be0v.x;
            a.y = (v.y - mu) * rs * g0v.y + be0v.y;
            a.z = (v.z - mu) * rs * g0v.z + be0v.z;
            a.w = (v.w - mu) * rs * g0v.w + be0v.w;
            *reinterpret_cast<float4*>(&Asm[r][4 * lane]) = a;
        }
    }
    __syncthreads();

    // ---- GEMM: thread = (c2 = tid&127 -> cols {2c2,2c2+1},
    //                      rg = tid>>7  -> rows rg*16 .. rg*16+15)
    // Per 4-k step: 4 coalesced float2 W3 loads + 16 wave-uniform b128 LDS
    // broadcasts + 128 FMA -> VALU-bound.
    const int c2 = tid & 127;
    const int rg = tid >> 7;

    float acc0[16], acc1[16];
    {
        const float2 bb = *reinterpret_cast<const float2*>(&b3[2 * c2]);
#pragma unroll
        for (int r = 0; r < 16; ++r) { acc0[r] = bb.x; acc1[r] = bb.y; }
    }

    const float* Arow = &Asm[rg * 16][0];
    for (int k = 0; k < HH; k += 4) {
        const float2 w0 = *reinterpret_cast<const float2*>(&W3[(size_t)(k + 0) * HH + 2 * c2]);
        const float2 w1 = *reinterpret_cast<const float2*>(&W3[(size_t)(k + 1) * HH + 2 * c2]);
        const float2 w2 = *reinterpret_cast<const float2*>(&W3[(size_t)(k + 2) * HH + 2 * c2]);
        const float2 w3 = *reinterpret_cast<const float2*>(&W3[(size_t)(k + 3) * HH + 2 * c2]);
#pragma unroll
        for (int r = 0; r < 16; ++r) {
            const float4 a = *reinterpret_cast<const float4*>(Arow + r * HH + k);
            float s0 = acc0[r], s1 = acc1[r];
            s0 = fmaf(a.x, w0.x, s0); s1 = fmaf(a.x, w0.y, s1);
            s0 = fmaf(a.y, w1.x, s0); s1 = fmaf(a.y, w1.y, s1);
            s0 = fmaf(a.z, w2.x, s0); s1 = fmaf(a.z, w2.y, s1);
            s0 = fmaf(a.w, w3.x, s0); s1 = fmaf(a.w, w3.y, s1);
            acc0[r] = s0; acc1[r] = s1;
        }
    }
    __syncthreads();   // everyone done reading A before Y overwrites it

    // ---- Y back into the LDS tile -----------------------------------------
#pragma unroll
    for (int r = 0; r < 16; ++r) {
        float2 o; o.x = acc0[r]; o.y = acc1[r];
        *reinterpret_cast<float2*>(&Ysm[(rg * 16 + r) * HH + 2 * c2]) = o;
    }
    __syncthreads();

    // ---- LN1 + relu + coalesced store -------------------------------------
    {
        const float4 g1v  = *reinterpret_cast<const float4*>(g1  + 4 * lane);
        const float4 be1v = *reinterpret_cast<const float4*>(be1 + 4 * lane);
        float* outb = out + (((size_t)b * NN + n) * TT + tile * TROWS) * HH;

#pragma unroll 2
        for (int i = 0; i < 8; ++i) {
            const int r = wave * 8 + i;
            const float4 y = *reinterpret_cast<const float4*>(&Ysm[r * HH + 4 * lane]);
            float s = y.x + y.y + y.z + y.w;
            float q = y.x * y.x + y.y * y.y + y.z * y.z + y.w * y.w;
#pragma unroll
            for (int off = 32; off >= 1; off >>= 1) {
                s += __shfl_xor(s, off, 64);
                q += __shfl_xor(q, off, 64);
            }
            const float mu  = s * (1.0f / HH);
            const float var = q * (1.0f / HH) - mu * mu;
            const float rs  = rsqrtf(var + EPSF);
            float4 o;
            o.x = fmaxf((y.x - mu) * rs * g1v.x + be1v.x, 0.0f);
            o.y = fmaxf((y.y - mu) * rs * g1v.y + be1v.y, 0.0f);
            o.z = fmaxf((y.z - mu) * rs * g1v.z + be1v.z, 0.0f);
            o.w = fmaxf((y.w - mu) * rs * g1v.w + be1v.w, 0.0f);
            *reinterpret_cast<float4*>(outb + (size_t)r * HH + 4 * lane) = o;
        }
    }
}

// ---------------------------------------------------------------------------
extern "C" void kernel_launch(void* const* d_in, const int* in_sizes, int n_in,
                              void* d_out, int out_size, void* d_ws, size_t ws_size,
                              hipStream_t stream) {
    const float* x1  = (const float*)d_in[0];
    const float* x2  = (const float*)d_in[1];
    const float* W1  = (const float*)d_in[2];
    const float* b1  = (const float*)d_in[3];
    const float* W2  = (const float*)d_in[4];
    const float* b2  = (const float*)d_in[5];
    const float* W3  = (const float*)d_in[6];
    const float* b3  = (const float*)d_in[7];
    const float* g0  = (const float*)d_in[8];
    const float* be0 = (const float*)d_in[9];
    const float* g1  = (const float*)d_in[10];
    const float* be1 = (const float*)d_in[11];
    float* out = (float*)d_out;

    // Workspace: h1 (512*256 f32) | h2 (4096*256 f32)  = 4.5 MB
    float* h1 = (float*)d_ws;
    float* h2 = h1 + (size_t)BB * NN * HH;

    hipLaunchKernelGGL(prep_kernel, dim3(576), dim3(256), 0, stream,
                       x1, x2, W1, b1, W2, b2, h1, h2);

    hipLaunchKernelGGL(fused_f32_kernel, dim3(4096), dim3(256), 0, stream,
                       h1, h2, W3, b3, g0, be0, g1, be1, out);
}